// Round 8
// baseline (9729.683 us; speedup 1.0000x reference)
//
#include <hip/hip_runtime.h>
#include <math.h>

typedef float f4 __attribute__((ext_vector_type(4)));
typedef _Float16 h8 __attribute__((ext_vector_type(8)));

// ---------------- workspace layout (float offsets), end = 32,112,640 = 128.45 MB (R4/R7-proven) ----
// AX  : A@x all t [i][t*128+b*2+c]      6,144,000
// AHC : A@[H0|H1] fp32 [1024][8192]     8,388,608   (Xr alias, dead before zero)
// HF  : H fp32 [1000][4096] (=[r][64])  4,096,000
// C0,C1: cell state fp32 [64000][64]    2 x 4,096,000   (At alias in C0, dead before zero)
// HTh/l: H^T split f16 [4096][1024]     2 x 2,097,152
// Ah/Al: split f16 A [1024][1024]       2 x 524,288
// W0h/l: Wh0 split f16 [256][64]  (in old W0T slot); W1h/l: [Wx1|Wh1] [256][128] (old W1T slot)
#define WS_AX    0
#define WS_AHC   6144000
#define WS_HF    14532608
#define WS_C0    18628608
#define WS_C1    22724608
#define WS_HTH   26820608
#define WS_HTL   28917760
#define WS_A16H  31014912
#define WS_A16L  31539200
#define WS_W0H   32063488
#define WS_W0L   32071680
#define WS_W1H   32079872
#define WS_W1L   32096256

// ---------------- A = softmax(relu(E1 @ E2^T)) in fp64, store A^T ----------------
__global__ __launch_bounds__(256) void compute_A(const float* __restrict__ E1,
                                                 const float* __restrict__ E2,
                                                 float* __restrict__ At)
{
    __shared__ double z[1000];
    __shared__ double red[256];
    __shared__ double e1[16];
    const int i = blockIdx.x;
    const int tid = threadIdx.x;
    if (tid < 16) e1[tid] = (double)E1[i * 16 + tid];
    __syncthreads();
    double lmax = -1e300;
    for (int j = tid; j < 1000; j += 256) {
        double s = 0.0;
        #pragma unroll
        for (int c = 0; c < 16; ++c) s += e1[c] * (double)E2[j * 16 + c];
        if (s < 0.0) s = 0.0;
        z[j] = s;
        if (s > lmax) lmax = s;
    }
    red[tid] = lmax; __syncthreads();
    for (int off = 128; off > 0; off >>= 1) {
        if (tid < off) red[tid] = fmax(red[tid], red[tid + off]);
        __syncthreads();
    }
    const double zmax = red[0];
    __syncthreads();
    double lsum = 0.0;
    for (int j = tid; j < 1000; j += 256) {
        double e = exp(z[j] - zmax);
        z[j] = e;
        lsum += e;
    }
    red[tid] = lsum; __syncthreads();
    for (int off = 128; off > 0; off >>= 1) {
        if (tid < off) red[tid] += red[tid + off];
        __syncthreads();
    }
    const double inv = 1.0 / red[0];
    for (int j = tid; j < 1000; j += 256)
        At[(size_t)j * 1000 + i] = (float)(z[j] * inv);
}

// ---------------- x [B,T,N,C] -> Xr [j][t*128 + b*2 + c] ----------------
__global__ __launch_bounds__(256) void transpose_x(const float* __restrict__ x,
                                                   float* __restrict__ Xr)
{
    int o = blockIdx.x * 256 + threadIdx.x;
    if (o >= 6144000) return;
    int j = o / 6144;
    int r = o - j * 6144;
    int t = r >> 7;
    int q = r & 127;
    int b = q >> 1;
    int c = q & 1;
    Xr[o] = x[(((size_t)(b * 48 + t)) * 1000 + j) * 2 + c];
}

__global__ __launch_bounds__(256) void zero_kernel(float* __restrict__ p, int n4)
{
    int i = blockIdx.x * 256 + threadIdx.x;
    if (i < n4) { f4 z = {0.f, 0.f, 0.f, 0.f}; ((f4*)p)[i] = z; }
}

// ---------------- weight split-f16 prep (once): W0 [256][64], W1 [256][128] k-major ----------------
__global__ __launch_bounds__(256) void prep_w2(const float* __restrict__ Wh0,
                                               const float* __restrict__ Wx1,
                                               const float* __restrict__ Wh1,
                                               _Float16* __restrict__ W0h,
                                               _Float16* __restrict__ W0l,
                                               _Float16* __restrict__ W1h,
                                               _Float16* __restrict__ W1l)
{
    int idx = blockIdx.x * 256 + threadIdx.x;
    if (idx < 16384) {                    // [256 gc][64 k] = torch layout of Wh0
        float v = Wh0[idx];
        _Float16 hi = (_Float16)v;
        W0h[idx] = hi;
        W0l[idx] = (_Float16)((v - (float)hi) * 2048.f);
    }
    int j = idx - 16384;
    if (j >= 0 && j < 32768) {            // [256 gc][128 k]: k<64 -> Wx1, k>=64 -> Wh1
        int gc = j >> 7, k = j & 127;
        float v = (k < 64) ? Wx1[gc * 64 + k] : Wh1[gc * 64 + (k - 64)];
        _Float16 hi = (_Float16)v;
        W1h[j] = hi;
        W1l[j] = (_Float16)((v - (float)hi) * 2048.f);
    }
}

// ---------------- split A^T fp32 -> Ah/Al f16 [m=1024][k=1024] ----------------
__global__ __launch_bounds__(256) void prep_A(const float* __restrict__ At,
                                              _Float16* __restrict__ Ahh,
                                              _Float16* __restrict__ All)
{
    int idx = blockIdx.x * 256 + threadIdx.x;   // 1,048,576
    int m = idx >> 10, k = idx & 1023;
    float v = (m < 1000 && k < 1000) ? At[(size_t)k * 1000 + m] : 0.f;
    _Float16 hi = (_Float16)v;
    Ahh[idx] = hi;
    All[idx] = (_Float16)((v - (float)hi) * 2048.f);
}

// ---------------- fp32 GEMM (used once for AX; R1-proven) ----------------
__global__ __launch_bounds__(256) void gemm1000(const float* __restrict__ At,
                                                const float* __restrict__ B,
                                                float* __restrict__ C,
                                                int ncols)
{
    __shared__ float As[8][64];
    __shared__ float Bs[8][128];
    const int tid = threadIdx.x;
    const int tx = tid & 15;
    const int ty = tid >> 4;
    const int row0 = blockIdx.x * 64;
    const int col0 = blockIdx.y * 128;
    const int lm = tid & 63;
    const int lk = tid >> 6;
    const int bcol = tid & 127;
    const int bk = tid >> 7;
    const bool arow_ok = (row0 + lm) < 1000;

    float acc[4][8];
    #pragma unroll
    for (int r = 0; r < 4; ++r)
        #pragma unroll
        for (int c = 0; c < 8; ++c) acc[r][c] = 0.f;

    for (int k0 = 0; k0 < 1000; k0 += 8) {
        float a0 = arow_ok ? At[(size_t)(k0 + lk) * 1000 + row0 + lm] : 0.f;
        float a1 = arow_ok ? At[(size_t)(k0 + lk + 4) * 1000 + row0 + lm] : 0.f;
        float bv[4];
        #pragma unroll
        for (int kk = 0; kk < 4; ++kk)
            bv[kk] = B[(size_t)(k0 + bk * 4 + kk) * ncols + col0 + bcol];
        __syncthreads();
        As[lk][lm] = a0;
        As[lk + 4][lm] = a1;
        #pragma unroll
        for (int kk = 0; kk < 4; ++kk) Bs[bk * 4 + kk][bcol] = bv[kk];
        __syncthreads();
        #pragma unroll
        for (int k = 0; k < 8; ++k) {
            f4 av = *(const f4*)&As[k][ty * 4];
            f4 b0 = *(const f4*)&Bs[k][tx * 8];
            f4 b1 = *(const f4*)&Bs[k][tx * 8 + 4];
            #pragma unroll
            for (int r = 0; r < 4; ++r) {
                float a = av[r];
                acc[r][0] = fmaf(a, b0[0], acc[r][0]);
                acc[r][1] = fmaf(a, b0[1], acc[r][1]);
                acc[r][2] = fmaf(a, b0[2], acc[r][2]);
                acc[r][3] = fmaf(a, b0[3], acc[r][3]);
                acc[r][4] = fmaf(a, b1[0], acc[r][4]);
                acc[r][5] = fmaf(a, b1[1], acc[r][5]);
                acc[r][6] = fmaf(a, b1[2], acc[r][6]);
                acc[r][7] = fmaf(a, b1[3], acc[r][7]);
            }
        }
    }
    #pragma unroll
    for (int r = 0; r < 4; ++r) {
        int row = row0 + ty * 4 + r;
        if (row < 1000) {
            f4 o0 = {acc[r][0], acc[r][1], acc[r][2], acc[r][3]};
            f4 o1 = {acc[r][4], acc[r][5], acc[r][6], acc[r][7]};
            *(f4*)&C[(size_t)row * ncols + col0 + tx * 8]     = o0;
            *(f4*)&C[(size_t)row * ncols + col0 + tx * 8 + 4] = o1;
        }
    }
}

// ---------------- H fp32 [i][4096] -> HT split f16 [4096][1024] (R4-proven) ----------------
__global__ __launch_bounds__(256) void transpose_split(const float* __restrict__ H,
                                                       _Float16* __restrict__ HTh,
                                                       _Float16* __restrict__ HTl)
{
    __shared__ float tile[32][33];
    const int tid = threadIdx.x;
    const int tx = tid & 31;
    const int ty = tid >> 5;
    const int n0 = blockIdx.x * 32;
    const int k0 = blockIdx.y * 32;
    #pragma unroll
    for (int j = 0; j < 4; ++j) {
        int k = k0 + ty * 4 + j;
        tile[ty * 4 + j][tx] = (k < 1000) ? H[(size_t)k * 4096 + n0 + tx] : 0.f;
    }
    __syncthreads();
    #pragma unroll
    for (int j = 0; j < 4; ++j) {
        int n = n0 + ty * 4 + j;
        float v = tile[tx][ty * 4 + j];
        _Float16 hi = (_Float16)v;
        size_t o = (size_t)n * 1024 + k0 + tx;
        HTh[o] = hi;
        HTl[o] = (_Float16)((v - (float)hi) * 2048.f);
    }
}

// ---------------- MFMA split-f16 GEMM (R7-proven): AHC[:, coloff:+4096] = A @ HT^T ----------------
#define GL16(srcp, dstoff) \
    __builtin_amdgcn_global_load_lds((const __attribute__((address_space(1))) unsigned int*)(srcp), \
        (__attribute__((address_space(3))) unsigned int*)(lds + (dstoff)), 16, 0, 0)

__device__ __forceinline__ int swzb(int row, int lg) {
    return row * 64 + ((lg ^ ((row ^ (row >> 2)) & 3)) << 4);
}

__global__ __launch_bounds__(256, 2) void gemm_ahv2(
    const _Float16* __restrict__ Ahg, const _Float16* __restrict__ Alg,
    const _Float16* __restrict__ Bhg, const _Float16* __restrict__ Blg,
    float* __restrict__ Cout, int coloff)
{
    __shared__ __align__(1024) char lds[24576];
    const int tid = threadIdx.x;
    const int lane = tid & 63;
    const int w = tid >> 6;
    const int lg = lane >> 4, l15 = lane & 15;
    const int m0 = (blockIdx.x & 15) * 64;
    const int n0 = (blockIdx.x >> 4) * 128;

    const int r16 = lane >> 2;
    const int sd = lane & 3;
    const char* src[6];
    #pragma unroll
    for (int q = 0; q < 6; ++q) {
        const int c = w * 6 + q;
        int row;
        const _Float16* g;
        if (c < 4)       { row = (c)      * 16 + r16; g = Ahg + (size_t)(m0 + row) * 1024; }
        else if (c < 8)  { row = (c - 4)  * 16 + r16; g = Alg + (size_t)(m0 + row) * 1024; }
        else if (c < 16) { row = (c - 8)  * 16 + r16; g = Bhg + (size_t)(n0 + row) * 1024; }
        else             { row = (c - 16) * 16 + r16; g = Blg + (size_t)(n0 + row) * 1024; }
        const int cg = sd ^ ((row ^ (row >> 2)) & 3);
        src[q] = (const char*)(g + cg * 8);
    }

    f4 acc0[4][2], acc1[4][2];
    #pragma unroll
    for (int a = 0; a < 4; ++a)
        #pragma unroll
        for (int b = 0; b < 2; ++b) {
            acc0[a][b] = (f4){0.f, 0.f, 0.f, 0.f};
            acc1[a][b] = (f4){0.f, 0.f, 0.f, 0.f};
        }

    for (int ks = 0; ks < 32; ++ks) {
        const int kadv = ks * 64;
        #pragma unroll
        for (int q = 0; q < 6; ++q)
            GL16(src[q] + kadv, (w * 6 + q) * 1024);
        __syncthreads();

        h8 fa[4], fl[4], bh[2], bl[2];
        #pragma unroll
        for (int mf = 0; mf < 4; ++mf) {
            const int ob = swzb(mf * 16 + l15, lg);
            fa[mf] = *(const h8*)(lds + ob);
            fl[mf] = *(const h8*)(lds + 4096 + ob);
        }
        #pragma unroll
        for (int nf = 0; nf < 2; ++nf) {
            const int ob = swzb(w * 32 + nf * 16 + l15, lg);
            bh[nf] = *(const h8*)(lds + 8192 + ob);
            bl[nf] = *(const h8*)(lds + 16384 + ob);
        }
        __syncthreads();

        #pragma unroll
        for (int nf = 0; nf < 2; ++nf)
            #pragma unroll
            for (int mf = 0; mf < 4; ++mf) {
                acc0[mf][nf] = __builtin_amdgcn_mfma_f32_16x16x32_f16(fa[mf], bh[nf], acc0[mf][nf], 0, 0, 0);
                acc1[mf][nf] = __builtin_amdgcn_mfma_f32_16x16x32_f16(fa[mf], bl[nf], acc1[mf][nf], 0, 0, 0);
                acc1[mf][nf] = __builtin_amdgcn_mfma_f32_16x16x32_f16(fl[mf], bh[nf], acc1[mf][nf], 0, 0, 0);
            }
    }

    #pragma unroll
    for (int mf = 0; mf < 4; ++mf)
        #pragma unroll
        for (int nf = 0; nf < 2; ++nf) {
            const int row = m0 + mf * 16 + lg * 4;
            const int col = coloff + n0 + w * 32 + nf * 16 + l15;
            #pragma unroll
            for (int e = 0; e < 4; ++e)
                Cout[(size_t)(row + e) * 8192 + col] =
                    acc0[mf][nf][e] + acc1[mf][nf][e] * (1.f / 2048.f);
        }
}

// ---------------- MFMA gates v3: LDS-staged, fp32 AH in, dense H/C out ----------------
// Block = node i: 64 rows b x 256 gc, K=64 (layer0) or 128 (layer1).
// A-tile = AHC[i*8192 + colbase ...] contiguous slab, fp32->split-f16 during staging.
// W from split-f16 [256][K] global, staged per 32-k chunk, 4 lanes/row (<=2-way LDS).
// Epilogue = gates_v2's dense [r][64] writes (64B runs).
__global__ __launch_bounds__(256) void gates_mfma3(
    const float* __restrict__ AHC, int K128,
    const _Float16* __restrict__ Wgh, const _Float16* __restrict__ Wgl,  // [256][K]
    const float* __restrict__ b1, const float* __restrict__ b2,
    const float* __restrict__ AX, const float* __restrict__ WxE, int t,
    float* __restrict__ Cst, float* __restrict__ Hout)
{
    __shared__ __align__(16) _Float16 Ahs[64 * 40];
    __shared__ __align__(16) _Float16 Als[64 * 40];
    __shared__ __align__(16) _Float16 Whs[256 * 40];
    __shared__ __align__(16) _Float16 Wls[256 * 40];
    const int tid = threadIdx.x;
    const int lane = tid & 63;
    const int w = tid >> 6;
    const int lg = lane >> 4, l15 = lane & 15;
    const int i = blockIdx.x;
    const int K = K128 ? 128 : 64;
    const int h = w * 16 + l15;
    const int sb = tid >> 2;          // 0..63 (row for A staging; row-within-64 for W)
    const int sk = (tid & 3) * 8;     // k-slot 0,8,16,24

    f4 acc0[4][4], acc1[4][4];        // [mf][gate]
    #pragma unroll
    for (int a = 0; a < 4; ++a)
        #pragma unroll
        for (int b = 0; b < 4; ++b) {
            acc0[a][b] = (f4){0.f, 0.f, 0.f, 0.f};
            acc1[a][b] = (f4){0.f, 0.f, 0.f, 0.f};
        }

    const int nks = K >> 5;
    for (int ks = 0; ks < nks; ++ks) {
        const int colbase = ((ks < 2) ? 0 : 4096) + (ks & 1) * 32;
        // --- A: 8 fp32 coalesced, split in reg ---
        const float* asrc = AHC + (size_t)i * 8192 + colbase + sb * 64 + sk;
        f4 a0 = *(const f4*)asrc;
        f4 a1 = *(const f4*)(asrc + 4);
        h8 avh, avl;
        #pragma unroll
        for (int j = 0; j < 4; ++j) {
            _Float16 hi0 = (_Float16)a0[j];
            avh[j] = hi0; avl[j] = (_Float16)((a0[j] - (float)hi0) * 2048.f);
            _Float16 hi1 = (_Float16)a1[j];
            avh[4 + j] = hi1; avl[4 + j] = (_Float16)((a1[j] - (float)hi1) * 2048.f);
        }
        // --- W: 4 passes x 8 k, 4 lanes per gc row ---
        h8 wvh[4], wvl[4];
        #pragma unroll
        for (int p = 0; p < 4; ++p) {
            const int gc = p * 64 + sb;
            const size_t wd = (size_t)gc * K + ks * 32 + sk;
            wvh[p] = *(const h8*)&Wgh[wd];
            wvl[p] = *(const h8*)&Wgl[wd];
        }
        __syncthreads();              // previous chunk fully consumed
        *(h8*)&Ahs[sb * 40 + sk] = avh;
        *(h8*)&Als[sb * 40 + sk] = avl;
        #pragma unroll
        for (int p = 0; p < 4; ++p) {
            *(h8*)&Whs[(p * 64 + sb) * 40 + sk] = wvh[p];
            *(h8*)&Wls[(p * 64 + sb) * 40 + sk] = wvl[p];
        }
        __syncthreads();
        // --- frags + MFMA (R6-proven core) ---
        h8 fa[4], fl[4];
        #pragma unroll
        for (int mf = 0; mf < 4; ++mf) {
            const int ao = (mf * 16 + l15) * 40 + lg * 8;
            fa[mf] = *(const h8*)&Ahs[ao];
            fl[mf] = *(const h8*)&Als[ao];
        }
        #pragma unroll
        for (int nf = 0; nf < 4; ++nf) {      // nf = gate
            const int bo = (nf * 64 + h) * 40 + lg * 8;
            const h8 bh = *(const h8*)&Whs[bo];
            const h8 bl = *(const h8*)&Wls[bo];
            #pragma unroll
            for (int mf = 0; mf < 4; ++mf) {
                acc0[mf][nf] = __builtin_amdgcn_mfma_f32_16x16x32_f16(fa[mf], bh, acc0[mf][nf], 0, 0, 0);
                acc1[mf][nf] = __builtin_amdgcn_mfma_f32_16x16x32_f16(fa[mf], bl, acc1[mf][nf], 0, 0, 0);
                acc1[mf][nf] = __builtin_amdgcn_mfma_f32_16x16x32_f16(fl[mf], bh, acc1[mf][nf], 0, 0, 0);
            }
        }
    }

    float bs[4], wx0[4], wx1v[4];
    #pragma unroll
    for (int g = 0; g < 4; ++g) {
        const int gc = g * 64 + h;
        bs[g] = b1[gc] + b2[gc];
        if (WxE) { wx0[g] = WxE[gc * 2]; wx1v[g] = WxE[gc * 2 + 1]; }
    }

    // C/D (m89-verified): col = gc (lane's h), row b = mf*16 + lg*4 + e
    #pragma unroll
    for (int mf = 0; mf < 4; ++mf) {
        #pragma unroll
        for (int e = 0; e < 4; ++e) {
            const int b = mf * 16 + lg * 4 + e;
            float gv[4];
            #pragma unroll
            for (int g = 0; g < 4; ++g)
                gv[g] = acc0[mf][g][e] + acc1[mf][g][e] * (1.f / 2048.f) + bs[g];
            if (AX) {
                const float x0 = AX[(size_t)i * 6144 + t * 128 + b * 2 + 0];
                const float x1 = AX[(size_t)i * 6144 + t * 128 + b * 2 + 1];
                #pragma unroll
                for (int g = 0; g < 4; ++g)
                    gv[g] = fmaf(x0, wx0[g], fmaf(x1, wx1v[g], gv[g]));
            }
            const float ig = 1.f / (1.f + expf(-gv[0]));
            const float fg = 1.f / (1.f + expf(-gv[1]));
            const float og = 1.f / (1.f + expf(-gv[2]));
            const float gg = tanhf(gv[3]);
            const size_t cb = ((size_t)(i * 64 + b)) * 64 + h;
            const float c = fg * Cst[cb] + ig * gg;
            Cst[cb] = c;
            Hout[cb] = og * tanhf(c);
        }
    }
}

// ---------------- final projection ----------------
__global__ __launch_bounds__(256) void proj_kernel(const float* __restrict__ H1,
                                                   const float* __restrict__ Wpj,
                                                   const float* __restrict__ bp,
                                                   float* __restrict__ out)
{
    int r = blockIdx.x * 256 + threadIdx.x;
    if (r >= 64000) return;
    int i = r >> 6, b = r & 63;
    f4 hv[16];
    #pragma unroll
    for (int q = 0; q < 16; ++q) hv[q] = *(const f4*)&H1[(size_t)r * 64 + q * 4];
    #pragma unroll
    for (int hor = 0; hor < 12; ++hor) {
        float s = bp[hor];
        #pragma unroll
        for (int q = 0; q < 16; ++q) {
            f4 w = *(const f4*)&Wpj[hor * 64 + q * 4];
            s = fmaf(hv[q][0], w[0], s);
            s = fmaf(hv[q][1], w[1], s);
            s = fmaf(hv[q][2], w[2], s);
            s = fmaf(hv[q][3], w[3], s);
        }
        out[(size_t)(b * 12 + hor) * 1000 + i] = s;
    }
}

extern "C" void kernel_launch(void* const* d_in, const int* in_sizes, int n_in,
                              void* d_out, int out_size, void* d_ws, size_t ws_size,
                              hipStream_t stream)
{
    const float* x   = (const float*)d_in[0];
    const float* E1  = (const float*)d_in[1];
    const float* E2  = (const float*)d_in[2];
    const float* Wx0 = (const float*)d_in[3];
    const float* bx0 = (const float*)d_in[4];
    const float* Wh0 = (const float*)d_in[5];
    const float* bh0 = (const float*)d_in[6];
    const float* Wx1 = (const float*)d_in[7];
    const float* bx1 = (const float*)d_in[8];
    const float* Wh1 = (const float*)d_in[9];
    const float* bh1 = (const float*)d_in[10];
    const float* Wp  = (const float*)d_in[11];
    const float* bp  = (const float*)d_in[12];
    float* out = (float*)d_out;
    float* ws  = (float*)d_ws;

    float*    AX  = ws + WS_AX;
    float*    AHC = ws + WS_AHC;
    float*    HF  = ws + WS_HF;
    float*    C0  = ws + WS_C0;
    float*    C1  = ws + WS_C1;
    _Float16* HTh = (_Float16*)(ws + WS_HTH);
    _Float16* HTl = (_Float16*)(ws + WS_HTL);
    _Float16* Ah  = (_Float16*)(ws + WS_A16H);
    _Float16* Al  = (_Float16*)(ws + WS_A16L);
    _Float16* W0h = (_Float16*)(ws + WS_W0H);
    _Float16* W0l = (_Float16*)(ws + WS_W0L);
    _Float16* W1h = (_Float16*)(ws + WS_W1H);
    _Float16* W1l = (_Float16*)(ws + WS_W1L);
    float*    At  = ws + WS_C0;    // alias: dead before C0/C1 zeroed
    float*    Xr  = ws + WS_AHC;   // alias: dead before AHC zeroed

    compute_A<<<1000, 256, 0, stream>>>(E1, E2, At);
    transpose_x<<<24000, 256, 0, stream>>>(x, Xr);
    gemm1000<<<dim3(16, 48), 256, 0, stream>>>(At, Xr, AX, 6144);   // AX = A @ Xr
    prep_w2<<<192, 256, 0, stream>>>(Wh0, Wx1, Wh1, W0h, W0l, W1h, W1l);
    prep_A<<<4096, 256, 0, stream>>>(At, Ah, Al);
    zero_kernel<<<8000, 256, 0, stream>>>(ws + WS_C0, 2048000);     // C0,C1 (kills At)
    zero_kernel<<<8192, 256, 0, stream>>>(AHC, 2097152);            // AHC (kills Xr)

    for (int t = 0; t < 48; ++t) {
        // layer 0: gates = (A@H0prev)[cols 0:4096] Wh0^T + x-path -> HF=H0new, C0
        gates_mfma3<<<1000, 256, 0, stream>>>(AHC, 0, W0h, W0l, bh0, bx0,
                                              AX, Wx0, t, C0, HF);
        transpose_split<<<dim3(128, 32), 256, 0, stream>>>(HF, HTh, HTl);
        gemm_ahv2<<<512, 256, 0, stream>>>(Ah, Al, HTh, HTl, AHC, 0);       // A@H0new
        // layer 1: gates = (A@H0new)Wx1^T + (A@H1prev)Wh1^T -> HF=H1new, C1
        gates_mfma3<<<1000, 256, 0, stream>>>(AHC, 1, W1h, W1l, bh1, bx1,
                                              nullptr, nullptr, 0, C1, HF);
        if (t < 47) {
            transpose_split<<<dim3(128, 32), 256, 0, stream>>>(HF, HTh, HTl);
            gemm_ahv2<<<512, 256, 0, stream>>>(Ah, Al, HTh, HTl, AHC, 4096); // A@H1new
        }
    }
    proj_kernel<<<250, 256, 0, stream>>>(HF, Wp, bp, out);
    (void)in_sizes; (void)n_in; (void)out_size; (void)ws_size;
}